// Round 7
// baseline (1565.965 us; speedup 1.0000x reference)
//
#include <hip/hip_runtime.h>

#define HDIM 64
#define NSTEPS 4

typedef float v2f __attribute__((ext_vector_type(2)));

// acc(VGPR pair) += w(SGPR pair, wave-uniform weights) * x(VGPR pair), packed f32.
// hipcc scalarizes __builtin_elementwise_fma on v2f (r3 evidence), so force VOP3P.
#define PK_FMA(acc, w, x) \
  asm("v_pk_fma_f32 %0, %1, %2, %0" : "+v"(acc) : "s"(w), "v"(x))

// Packed weight layout in d_ws (float offsets)  [identical to round-5 layout]:
//   [0,    256): L1 pack: per k, float4 (W1[k][0], W1[k][1], W1[k][2], b1[k])
//   [256, 4352): W2T[k][j] = W2[j][k+1]                  (64x64)
//   [4352,8448): QT[k][j]  = P[k][j] * W2[j][k+1]        (64x64)
//                where P[k][j] = W1[k][1]*W3[0][j+1] + W1[k][2]*W3[1][j+1]
//   [8448,8576): C2 per j: float2 (W2[j][0], b2[j])
//   [8576,8704): L3 per j: float2 (W3[0][j+1], W3[1][j+1])
//   [8704,8708): C3: (W3[0][0], W3[1][0], b3[0], b3[1])

__global__ void ffjord_prep(const float* __restrict__ W1, const float* __restrict__ b1,
                            const float* __restrict__ W2, const float* __restrict__ b2,
                            const float* __restrict__ W3, const float* __restrict__ b3,
                            float* __restrict__ ws) {
  int tid = threadIdx.x;  // single block, 256 threads
  if (tid < HDIM) {
    ws[tid * 4 + 0] = W1[tid * 3 + 0];
    ws[tid * 4 + 1] = W1[tid * 3 + 1];
    ws[tid * 4 + 2] = W1[tid * 3 + 2];
    ws[tid * 4 + 3] = b1[tid];
    ws[8448 + tid * 2 + 0] = W2[tid * 65 + 0];
    ws[8448 + tid * 2 + 1] = b2[tid];
    ws[8576 + tid * 2 + 0] = W3[0 * 65 + tid + 1];
    ws[8576 + tid * 2 + 1] = W3[1 * 65 + tid + 1];
  }
  if (tid == 0) {
    ws[8704] = W3[0];
    ws[8705] = W3[65];
    ws[8706] = b3[0];
    ws[8707] = b3[1];
  }
  for (int e = tid; e < HDIM * HDIM; e += 256) {
    int k = e >> 6, j = e & 63;
    float w2 = W2[j * 65 + k + 1];
    float p = W1[k * 3 + 1] * W3[j + 1] + W1[k * 3 + 2] * W3[65 + j + 1];
    ws[256 + e] = w2;       // W2T[k][j]
    ws[4352 + e] = p * w2;  // QT[k][j]
  }
}

// One point per thread; all weight rows wave-uniform (s_load broadcast, "s"
// asm constraints). Quad-pass over j-halves: per half {pass A -> h2-half
// (16 v2f = 32 regs), mid -> g-half in place, pass B -> dv partial}. Peak
// live ~= 32 + ~24 state/temps < the (256,4) 64-reg cap -> 4 waves/SIMD
// WITHOUT spill (r1/r4 hit this cap with 120+-float live sets and spilled;
// this live set genuinely fits). All math f32 (the r6 f16 experiment failed
// the logpz tolerance); pk_fma stream identical to r5 (4096/eval), layer-1
// chains recomputed 2x (+~20% issues) to buy ~2x residency while
// latency-bound. Checkpoint: WRITE_SIZE must stay ~3 MB (no scratch).
__global__ __launch_bounds__(256, 4) void ffjord_main(
    const float* __restrict__ z_in, const float* __restrict__ dlp_in,
    const float* __restrict__ ws, float* __restrict__ out, int B) {
  int i = blockIdx.x * 256 + threadIdx.x;
  if (i >= B) return;

  const float4* L1  = (const float4*)(ws);
  const float*  W2T = ws + 256;
  const float*  QT  = ws + 4352;
  const float2* C2  = (const float2*)(ws + 8448);
  const v2f*    L3v = (const v2f*)(ws + 8576);  // per j: (W3[0][j+1], W3[1][j+1])
  const float c30 = ws[8704], c31 = ws[8705], cb0 = ws[8706], cb1 = ws[8707];

  float z0 = z_in[2 * i], z1 = z_in[2 * i + 1];
  float l = dlp_in[i];
  const float dt = 1.0f / NSTEPS;

  #pragma unroll 1
  for (int step = 0; step < NSTEPS; ++step) {
    float t0 = step * dt;
    float az0 = 0.f, az1 = 0.f, al = 0.f;
    float zt0 = z0, zt1 = z1, ts = t0;

    #pragma unroll 1
    for (int s = 0; s < 4; ++s) {
      // ---- dynamics eval at (ts, zt), split over two j-halves ----
      v2f zdv;  // (zd0, zd1) packed
      zdv.x = fmaf(c30, ts, cb0);
      zdv.y = fmaf(c31, ts, cb1);
      float dv = 0.f;

      #pragma unroll 1
      for (int hh = 0; hh < 2; ++hh) {
        const float* w2base = W2T + 32 * hh;  // wave-uniform half-row bases
        const float* qbase  = QT + 32 * hh;

        // Pass A (half hh): h2[j] = c2_j(t) + sum_k W2T[k][j]*softplus(a_k)
        v2f h2[16];
        #pragma unroll
        for (int m = 0; m < 16; ++m) {
          float2 ca = C2[32 * hh + 2 * m], cb2 = C2[32 * hh + 2 * m + 1];
          v2f v;
          v.x = fmaf(ca.x, ts, ca.y);
          v.y = fmaf(cb2.x, ts, cb2.y);
          h2[m] = v;
        }

        #pragma unroll 1
        for (int k = 0; k < HDIM; ++k) {
          float4 w1 = L1[k];  // wave-uniform -> s_load
          float a = fmaf(w1.x, ts, fmaf(w1.y, zt0, fmaf(w1.z, zt1, w1.w)));
          float e = __expf(-fabsf(a));
          float sp = fmaxf(a, 0.f) + __logf(1.0f + e);    // softplus(a)
          const v2f* row = (const v2f*)(w2base + k * 64); // wave-uniform row
          v2f spv = {sp, sp};
          #pragma unroll
          for (int m = 0; m < 16; ++m)
            PK_FMA(h2[m], row[m], spv);
        }

        // Mid (half hh): zd += L3*softplus(h2); overwrite h2 with sigmoid(h2)
        #pragma unroll
        for (int m = 0; m < 16; ++m) {
          v2f hv = h2[m];
          v2f gv;
          #pragma unroll
          for (int c = 0; c < 2; ++c) {
            float a = hv[c];
            float e = __expf(-fabsf(a));
            float r = __builtin_amdgcn_rcpf(1.0f + e);
            float sg = (a >= 0.f ? 1.0f : e) * r;        // sigmoid
            float sp = fmaxf(a, 0.f) + __logf(1.0f + e); // softplus
            v2f spv = {sp, sp};
            PK_FMA(zdv, L3v[32 * hh + 2 * m + c], spv);
            gv[c] = sg;
          }
          h2[m] = gv;  // now holds g
        }

        // Pass B (half hh): dv += sum_k sigmoid(a_k) * (QT[k][half] . g)
        #pragma unroll 1
        for (int k = 0; k < HDIM; ++k) {
          float4 w1 = L1[k];
          float a = fmaf(w1.x, ts, fmaf(w1.y, zt0, fmaf(w1.z, zt1, w1.w)));
          float e = __expf(-fabsf(a));
          float r = __builtin_amdgcn_rcpf(1.0f + e);
          float sg = (a >= 0.f ? 1.0f : e) * r;          // sigmoid(a_k)
          const v2f* qrow = (const v2f*)(qbase + k * 64);
          v2f d0 = {0.f, 0.f}, d1 = {0.f, 0.f};
          #pragma unroll
          for (int m = 0; m < 16; m += 2) {
            PK_FMA(d0, qrow[m], h2[m]);
            PK_FMA(d1, qrow[m + 1], h2[m + 1]);
          }
          v2f ds = d0 + d1;
          dv = fmaf(sg, ds.x + ds.y, dv);
        }
      }
      float zd0 = zdv.x, zd1 = zdv.y;

      // ---- RK4 combine ----
      float w = (s == 1 || s == 2) ? 2.0f : 1.0f;
      az0 = fmaf(w, zd0, az0);
      az1 = fmaf(w, zd1, az1);
      al = fmaf(w, dv, al);
      if (s < 3) {
        float c = (s == 2) ? dt : 0.5f * dt;
        zt0 = fmaf(c, zd0, z0);
        zt1 = fmaf(c, zd1, z1);
        ts = t0 + c;
      }
    }
    z0 = fmaf(dt / 6.0f, az0, z0);
    z1 = fmaf(dt / 6.0f, az1, z1);
    l = fmaf(-dt / 6.0f, al, l);  // k_l = -div
  }

  out[2 * i] = z0;
  out[2 * i + 1] = z1;
  out[2 * B + i] = l;
}

extern "C" void kernel_launch(void* const* d_in, const int* in_sizes, int n_in,
                              void* d_out, int out_size, void* d_ws, size_t ws_size,
                              hipStream_t stream) {
  const float* z   = (const float*)d_in[0];
  const float* dlp = (const float*)d_in[1];
  const float* W1  = (const float*)d_in[2];
  const float* b1  = (const float*)d_in[3];
  const float* W2  = (const float*)d_in[4];
  const float* b2  = (const float*)d_in[5];
  const float* W3  = (const float*)d_in[6];
  const float* b3  = (const float*)d_in[7];
  float* out = (float*)d_out;
  float* ws = (float*)d_ws;

  int B = in_sizes[0] / 2;

  ffjord_prep<<<1, 256, 0, stream>>>(W1, b1, W2, b2, W3, b3, ws);
  int blocks = (B + 255) / 256;
  ffjord_main<<<blocks, 256, 0, stream>>>(z, dlp, ws, out, B);
}

// Round 8
// 896.846 us; speedup vs baseline: 1.7461x; 1.7461x over previous
//
#include <hip/hip_runtime.h>

#define HDIM 64
#define NSTEPS 4

typedef __attribute__((ext_vector_type(4))) float f32x4;
typedef __attribute__((ext_vector_type(8))) short bf16x8;
typedef unsigned int uint;

union FragU { uint u[4]; uint4 u4; bf16x8 v; };

__device__ inline uint cvt_pk_bf16(float a, float b) {
  uint d;
  asm("v_cvt_pk_bf16_f32 %0, %1, %2" : "=v"(d) : "v"(a), "v"(b));
  return d;  // low16 = bf16(a), high16 = bf16(b), RNE
}
__device__ inline float lo_bf16_f32(uint p) { return __builtin_bit_cast(float, p << 16); }
__device__ inline float hi_bf16_f32(uint p) { return __builtin_bit_cast(float, p & 0xFFFF0000u); }

__device__ inline unsigned short rne_bf16u(float x) {
  uint u = __builtin_bit_cast(uint, x);
  uint r = u + 0x7FFFu + ((u >> 16) & 1u);
  return (unsigned short)(r >> 16);
}
__device__ inline float bf16f(unsigned short h) { return __builtin_bit_cast(float, ((uint)h) << 16); }

// ws layout (dword offsets):
//   [0,    8192): fragment planes, 2048 dw each:
//       mat0 = W2T hi, mat1 = W2T lo, mat2 = QT hi, mat3 = QT lo
//     dword index within plane: ((kt*4+nt)*64 + lane)*4 + d
//     element pair (2d, 2d+1):  k = kt*32 + (lane>>4)*8 + 2d+c, n(j) = nt*16 + (lane&15)
//     W2T[k][j] = W2[j][k+1];  QT[k][j] = (W1[k][1]*W3[0][j+1]+W1[k][2]*W3[1][j+1])*W2[j][k+1]
//   [8192, 8448): L1 per k: float4 (W1[k][0], W1[k][1], W1[k][2], b1[k])
//   [8448, 8576): C2 per j: float2 (W2[j][0], b2[j])
//   [8576, 8704): L3 per j: float2 (W3[0][j+1], W3[1][j+1])
//   [8704, 8708): C3: (W3[0][0], W3[1][0], b3[0], b3[1])

__global__ void ffjord_prep(const float* __restrict__ W1, const float* __restrict__ b1,
                            const float* __restrict__ W2, const float* __restrict__ b2,
                            const float* __restrict__ W3, const float* __restrict__ b3,
                            float* __restrict__ ws) {
  int tid = threadIdx.x;  // single block, 256 threads
  uint* wsu = (uint*)ws;
  for (int e2 = tid; e2 < 8192; e2 += 256) {
    int mat = e2 >> 11;
    int rem = e2 & 2047;
    int fr  = rem >> 8;          // kt*4+nt
    int l   = (rem >> 2) & 63;
    int d   = rem & 3;
    int kt = fr >> 2, nt = fr & 3;
    int g = l >> 4, cc = l & 15;
    int k0 = kt * 32 + g * 8 + 2 * d;
    int j  = nt * 16 + cc;
    float v0, v1;
    if (mat < 2) {
      v0 = W2[j * 65 + k0 + 1];
      v1 = W2[j * 65 + k0 + 2];
    } else {
      float p0 = W1[k0 * 3 + 1] * W3[j + 1] + W1[k0 * 3 + 2] * W3[65 + j + 1];
      float p1 = W1[(k0 + 1) * 3 + 1] * W3[j + 1] + W1[(k0 + 1) * 3 + 2] * W3[65 + j + 1];
      v0 = p0 * W2[j * 65 + k0 + 1];
      v1 = p1 * W2[j * 65 + k0 + 2];
    }
    unsigned short h0 = rne_bf16u(v0), h1 = rne_bf16u(v1);
    if (mat & 1) {  // lo plane = bf16 of residual
      h0 = rne_bf16u(v0 - bf16f(h0));
      h1 = rne_bf16u(v1 - bf16f(h1));
    }
    wsu[e2] = (uint)h0 | ((uint)h1 << 16);
  }
  if (tid < HDIM) {
    ws[8192 + tid * 4 + 0] = W1[tid * 3 + 0];
    ws[8192 + tid * 4 + 1] = W1[tid * 3 + 1];
    ws[8192 + tid * 4 + 2] = W1[tid * 3 + 2];
    ws[8192 + tid * 4 + 3] = b1[tid];
    ws[8448 + tid * 2 + 0] = W2[tid * 65 + 0];
    ws[8448 + tid * 2 + 1] = b2[tid];
    ws[8576 + tid * 2 + 0] = W3[tid + 1];
    ws[8576 + tid * 2 + 1] = W3[65 + tid + 1];
  }
  if (tid == 0) {
    ws[8704] = W3[0];
    ws[8705] = W3[65];
    ws[8706] = b3[0];
    ws[8707] = b3[1];
  }
}

// Per wave = 64 points. Both matvecs run as 64x64x64 GEMMs on the matrix pipe
// via mfma_f32_16x16x32_bf16, 3-term bf16 hi/lo split products (f16 single
// failed r6; bf16-split rel ~1e-5). Weight fragments prepacked by prep, read
// from LDS per eval (no per-k s_load latency — the diagnosed r0-r7 wall).
// All cross-lane glue is within-wave: zero barriers in the main loop.
__global__ void ffjord_main(
    const float* __restrict__ z_in, const float* __restrict__ dlp_in,
    const float* __restrict__ ws, float* __restrict__ out, int B) {
  __shared__ uint4 fragLds[2048];        // 32 KB: 4 planes x 512 uint4
  __shared__ float4 l1Lds[64];           // 1 KB
  __shared__ float2 c2Lds[64];           // 512 B
  __shared__ float2 l3Lds[64];           // 512 B
  __shared__ float2 stateLds[4][64];     // 2 KB  (per-wave zt broadcast)
  __shared__ float  redLds[4][3][64][4]; // 12 KB (per-wave zd0/zd1/dv reduce)

  int tid = threadIdx.x;
  const uint4* wsu4 = (const uint4*)ws;
  #pragma unroll
  for (int j = 0; j < 8; ++j) fragLds[tid + 256 * j] = wsu4[tid + 256 * j];
  if (tid < 64) {
    l1Lds[tid] = ((const float4*)(ws + 8192))[tid];
    c2Lds[tid] = ((const float2*)(ws + 8448))[tid];
    l3Lds[tid] = ((const float2*)(ws + 8576))[tid];
  }
  __syncthreads();

  const float c30 = ws[8704], c31 = ws[8705], cb0 = ws[8706], cb1 = ws[8707];

  int wid = tid >> 6, l = tid & 63;
  int g = l >> 4, c = l & 15;
  int pt = blockIdx.x * 256 + wid * 64 + l;
  int ptc = pt < B ? pt : (B - 1);

  float z0 = z_in[2 * ptc], z1 = z_in[2 * ptc + 1];
  float lp = dlp_in[ptc];
  const float dt = 1.0f / NSTEPS;

  // per-lane n-constants (n = nt*16 + c)
  float2 c2v[4], l3v[4];
  #pragma unroll
  for (int nt = 0; nt < 4; ++nt) {
    c2v[nt] = c2Lds[nt * 16 + c];
    l3v[nt] = l3Lds[nt * 16 + c];
  }

  #pragma unroll 1
  for (int step = 0; step < NSTEPS; ++step) {
    float t0 = step * dt;
    float az0 = 0.f, az1 = 0.f, al = 0.f;
    float zt0 = z0, zt1 = z1, ts = t0;

    #pragma unroll 1
    for (int s = 0; s < 4; ++s) {
      // ---- publish zt (owner), gather zt for this lane's 4 A-rows ----
      stateLds[wid][l] = make_float2(zt0, zt1);
      float mzt0[4], mzt1[4];
      #pragma unroll
      for (int mt = 0; mt < 4; ++mt) {
        float2 sv = stateLds[wid][mt * 16 + c];
        mzt0[mt] = sv.x; mzt1[mt] = sv.y;
      }
      float c2n[4];
      #pragma unroll
      for (int nt = 0; nt < 4; ++nt) c2n[nt] = fmaf(c2v[nt].x, ts, c2v[nt].y);

      // ---------- P1: softplus A-frags + GEMM1 (H2 = SP * W2T) ----------
      f32x4 C1[4][4];
      #pragma unroll
      for (int mt = 0; mt < 4; ++mt)
        #pragma unroll
        for (int nt = 0; nt < 4; ++nt)
          C1[mt][nt] = (f32x4){0.f, 0.f, 0.f, 0.f};

      #pragma unroll 1
      for (int kt = 0; kt < 2; ++kt) {
        float4 par[8]; float cts[8];
        #pragma unroll
        for (int e = 0; e < 8; ++e) {
          par[e] = l1Lds[kt * 32 + g * 8 + e];
          cts[e] = fmaf(par[e].x, ts, par[e].w);
        }
        FragU Ahi[4], Alo[4];
        #pragma unroll
        for (int mt = 0; mt < 4; ++mt) {
          float sp[8];
          #pragma unroll
          for (int e = 0; e < 8; ++e) {
            float a = fmaf(par[e].y, mzt0[mt], fmaf(par[e].z, mzt1[mt], cts[e]));
            float ex = __expf(-fabsf(a));
            sp[e] = fmaxf(a, 0.f) + __logf(1.0f + ex);  // softplus
          }
          #pragma unroll
          for (int d = 0; d < 4; ++d) {
            uint h = cvt_pk_bf16(sp[2 * d], sp[2 * d + 1]);
            float r0 = sp[2 * d]     - lo_bf16_f32(h);
            float r1 = sp[2 * d + 1] - hi_bf16_f32(h);
            Ahi[mt].u[d] = h;
            Alo[mt].u[d] = cvt_pk_bf16(r0, r1);
          }
        }
        #pragma unroll
        for (int nt = 0; nt < 4; ++nt) {
          FragU Bh, Bl;
          Bh.u4 = fragLds[0 * 512 + (kt * 4 + nt) * 64 + l];
          Bl.u4 = fragLds[1 * 512 + (kt * 4 + nt) * 64 + l];
          #pragma unroll
          for (int mt = 0; mt < 4; ++mt) {
            C1[mt][nt] = __builtin_amdgcn_mfma_f32_16x16x32_bf16(Ahi[mt].v, Bh.v, C1[mt][nt], 0, 0, 0);
            C1[mt][nt] = __builtin_amdgcn_mfma_f32_16x16x32_bf16(Ahi[mt].v, Bl.v, C1[mt][nt], 0, 0, 0);
            C1[mt][nt] = __builtin_amdgcn_mfma_f32_16x16x32_bf16(Alo[mt].v, Bh.v, C1[mt][nt], 0, 0, 0);
          }
        }
      }

      // ---------- P2: mid — zd partials, g = sigmoid(h2) (split-packed) ----------
      float zdp0[4][4], zdp1[4][4];
      uint gq[4][4][4];  // [mt][nt][{hi01,hi23,lo01,lo23}]
      #pragma unroll
      for (int mt = 0; mt < 4; ++mt)
        #pragma unroll
        for (int r = 0; r < 4; ++r) { zdp0[mt][r] = 0.f; zdp1[mt][r] = 0.f; }

      #pragma unroll
      for (int mt = 0; mt < 4; ++mt) {
        #pragma unroll
        for (int nt = 0; nt < 4; ++nt) {
          float gg[4];
          #pragma unroll
          for (int r = 0; r < 4; ++r) {
            float h2 = C1[mt][nt][r] + c2n[nt];
            float ex = __expf(-fabsf(h2));
            float rc = __builtin_amdgcn_rcpf(1.0f + ex);
            float sg = (h2 >= 0.f ? 1.0f : ex) * rc;      // sigmoid
            float sq = fmaxf(h2, 0.f) + __logf(1.0f + ex); // softplus
            zdp0[mt][r] = fmaf(l3v[nt].x, sq, zdp0[mt][r]);
            zdp1[mt][r] = fmaf(l3v[nt].y, sq, zdp1[mt][r]);
            gg[r] = sg;
          }
          uint h01 = cvt_pk_bf16(gg[0], gg[1]);
          uint h23 = cvt_pk_bf16(gg[2], gg[3]);
          gq[mt][nt][0] = h01;
          gq[mt][nt][1] = h23;
          gq[mt][nt][2] = cvt_pk_bf16(gg[0] - lo_bf16_f32(h01), gg[1] - hi_bf16_f32(h01));
          gq[mt][nt][3] = cvt_pk_bf16(gg[2] - lo_bf16_f32(h23), gg[3] - hi_bf16_f32(h23));
        }
      }

      // zd reduce: 2-step butterfly over c, 4 cluster slots to LDS
      #pragma unroll
      for (int mt = 0; mt < 4; ++mt)
        #pragma unroll
        for (int r = 0; r < 4; ++r) {
          zdp0[mt][r] += __shfl_xor(zdp0[mt][r], 1);
          zdp0[mt][r] += __shfl_xor(zdp0[mt][r], 2);
          zdp1[mt][r] += __shfl_xor(zdp1[mt][r], 1);
          zdp1[mt][r] += __shfl_xor(zdp1[mt][r], 2);
        }
      if ((c & 3) == 0) {
        int slot = c >> 2;
        #pragma unroll
        for (int mt = 0; mt < 4; ++mt)
          #pragma unroll
          for (int r = 0; r < 4; ++r) {
            int m = mt * 16 + g * 4 + r;
            redLds[wid][0][m][slot] = zdp0[mt][r];
            redLds[wid][1][m][slot] = zdp1[mt][r];
          }
      }

      // ---------- P3: sigmoid A-frags (a_k recomputed — cheap) ----------
      FragU SGhi[2][4], SGlo[2][4];
      #pragma unroll
      for (int kt = 0; kt < 2; ++kt) {
        float4 par[8]; float cts[8];
        #pragma unroll
        for (int e = 0; e < 8; ++e) {
          par[e] = l1Lds[kt * 32 + g * 8 + e];
          cts[e] = fmaf(par[e].x, ts, par[e].w);
        }
        #pragma unroll
        for (int mt = 0; mt < 4; ++mt) {
          float sgv[8];
          #pragma unroll
          for (int e = 0; e < 8; ++e) {
            float a = fmaf(par[e].y, mzt0[mt], fmaf(par[e].z, mzt1[mt], cts[e]));
            float ex = __expf(-fabsf(a));
            float rc = __builtin_amdgcn_rcpf(1.0f + ex);
            sgv[e] = (a >= 0.f ? 1.0f : ex) * rc;  // sigmoid
          }
          #pragma unroll
          for (int d = 0; d < 4; ++d) {
            uint h = cvt_pk_bf16(sgv[2 * d], sgv[2 * d + 1]);
            float r0 = sgv[2 * d]     - lo_bf16_f32(h);
            float r1 = sgv[2 * d + 1] - hi_bf16_f32(h);
            SGhi[kt][mt].u[d] = h;
            SGlo[kt][mt].u[d] = cvt_pk_bf16(r0, r1);
          }
        }
      }

      // ---------- P4: GEMM2 (R = SG * QT) per n-tile, dv += R .* g ----------
      float dvp[4][4];
      #pragma unroll
      for (int mt = 0; mt < 4; ++mt)
        #pragma unroll
        for (int r = 0; r < 4; ++r) dvp[mt][r] = 0.f;

      #pragma unroll
      for (int nt = 0; nt < 4; ++nt) {
        f32x4 C2[4];
        #pragma unroll
        for (int mt = 0; mt < 4; ++mt) C2[mt] = (f32x4){0.f, 0.f, 0.f, 0.f};
        #pragma unroll
        for (int kt = 0; kt < 2; ++kt) {
          FragU Bh, Bl;
          Bh.u4 = fragLds[2 * 512 + (kt * 4 + nt) * 64 + l];
          Bl.u4 = fragLds[3 * 512 + (kt * 4 + nt) * 64 + l];
          #pragma unroll
          for (int mt = 0; mt < 4; ++mt) {
            C2[mt] = __builtin_amdgcn_mfma_f32_16x16x32_bf16(SGhi[kt][mt].v, Bh.v, C2[mt], 0, 0, 0);
            C2[mt] = __builtin_amdgcn_mfma_f32_16x16x32_bf16(SGhi[kt][mt].v, Bl.v, C2[mt], 0, 0, 0);
            C2[mt] = __builtin_amdgcn_mfma_f32_16x16x32_bf16(SGlo[kt][mt].v, Bh.v, C2[mt], 0, 0, 0);
          }
        }
        #pragma unroll
        for (int mt = 0; mt < 4; ++mt) {
          float g0 = lo_bf16_f32(gq[mt][nt][0]) + lo_bf16_f32(gq[mt][nt][2]);
          float g1 = hi_bf16_f32(gq[mt][nt][0]) + hi_bf16_f32(gq[mt][nt][2]);
          float g2 = lo_bf16_f32(gq[mt][nt][1]) + lo_bf16_f32(gq[mt][nt][3]);
          float g3 = hi_bf16_f32(gq[mt][nt][1]) + hi_bf16_f32(gq[mt][nt][3]);
          dvp[mt][0] = fmaf(C2[mt][0], g0, dvp[mt][0]);
          dvp[mt][1] = fmaf(C2[mt][1], g1, dvp[mt][1]);
          dvp[mt][2] = fmaf(C2[mt][2], g2, dvp[mt][2]);
          dvp[mt][3] = fmaf(C2[mt][3], g3, dvp[mt][3]);
        }
      }

      // dv reduce
      #pragma unroll
      for (int mt = 0; mt < 4; ++mt)
        #pragma unroll
        for (int r = 0; r < 4; ++r) {
          dvp[mt][r] += __shfl_xor(dvp[mt][r], 1);
          dvp[mt][r] += __shfl_xor(dvp[mt][r], 2);
        }
      if ((c & 3) == 0) {
        int slot = c >> 2;
        #pragma unroll
        for (int mt = 0; mt < 4; ++mt)
          #pragma unroll
          for (int r = 0; r < 4; ++r)
            redLds[wid][2][mt * 16 + g * 4 + r][slot] = dvp[mt][r];
      }

      // ---------- owner: collect zd/dv, RK4 ----------
      float zd0, zd1, dv;
      {
        const float* r0p = &redLds[wid][0][l][0];
        const float* r1p = &redLds[wid][1][l][0];
        const float* r2p = &redLds[wid][2][l][0];
        zd0 = ((r0p[0] + r0p[1]) + (r0p[2] + r0p[3])) + fmaf(c30, ts, cb0);
        zd1 = ((r1p[0] + r1p[1]) + (r1p[2] + r1p[3])) + fmaf(c31, ts, cb1);
        dv  = (r2p[0] + r2p[1]) + (r2p[2] + r2p[3]);
      }

      float w = (s == 1 || s == 2) ? 2.0f : 1.0f;
      az0 = fmaf(w, zd0, az0);
      az1 = fmaf(w, zd1, az1);
      al  = fmaf(w, dv, al);
      if (s < 3) {
        float cc2 = (s == 2) ? dt : 0.5f * dt;
        zt0 = fmaf(cc2, zd0, z0);
        zt1 = fmaf(cc2, zd1, z1);
        ts = t0 + cc2;
      }
    }
    z0 = fmaf(dt / 6.0f, az0, z0);
    z1 = fmaf(dt / 6.0f, az1, z1);
    lp = fmaf(-dt / 6.0f, al, lp);  // k_l = -div
  }

  if (pt < B) {
    out[2 * pt] = z0;
    out[2 * pt + 1] = z1;
    out[2 * B + pt] = lp;
  }
}

extern "C" void kernel_launch(void* const* d_in, const int* in_sizes, int n_in,
                              void* d_out, int out_size, void* d_ws, size_t ws_size,
                              hipStream_t stream) {
  const float* z   = (const float*)d_in[0];
  const float* dlp = (const float*)d_in[1];
  const float* W1  = (const float*)d_in[2];
  const float* b1  = (const float*)d_in[3];
  const float* W2  = (const float*)d_in[4];
  const float* b2  = (const float*)d_in[5];
  const float* W3  = (const float*)d_in[6];
  const float* b3  = (const float*)d_in[7];
  float* out = (float*)d_out;
  float* ws = (float*)d_ws;

  int B = in_sizes[0] / 2;

  ffjord_prep<<<1, 256, 0, stream>>>(W1, b1, W2, b2, W3, b3, ws);
  int blocks = (B + 255) / 256;  // 256 points per block, 64 per wave
  ffjord_main<<<blocks, 256, 0, stream>>>(z, dlp, ws, out, B);
}

// Round 9
// 637.575 us; speedup vs baseline: 2.4561x; 1.4067x over previous
//
#include <hip/hip_runtime.h>

#define HDIM 64
#define NSTEPS 4

typedef __attribute__((ext_vector_type(4))) float f32x4;
typedef __attribute__((ext_vector_type(8))) short bf16x8;
typedef unsigned int uint;

union FragU { uint u[4]; uint4 u4; bf16x8 v; };

__device__ inline uint cvt_pk_bf16(float a, float b) {
  uint d;
  asm("v_cvt_pk_bf16_f32 %0, %1, %2" : "=v"(d) : "v"(a), "v"(b));
  return d;  // low16 = bf16(a), high16 = bf16(b), RNE
}
__device__ inline float lo_bf16_f32(uint p) { return __builtin_bit_cast(float, p << 16); }
__device__ inline float hi_bf16_f32(uint p) { return __builtin_bit_cast(float, p & 0xFFFF0000u); }

__device__ inline unsigned short rne_bf16u(float x) {
  uint u = __builtin_bit_cast(uint, x);
  uint r = u + 0x7FFFu + ((u >> 16) & 1u);
  return (unsigned short)(r >> 16);
}
__device__ inline float bf16f(unsigned short h) { return __builtin_bit_cast(float, ((uint)h) << 16); }

// ws layout (dword offsets) — identical to round 8:
//   [0,    8192): fragment planes, 2048 dw each:
//       mat0 = W2T hi, mat1 = W2T lo, mat2 = QT hi, mat3 = QT lo
//     dword index within plane: ((kt*4+nt)*64 + lane)*4 + d
//     element pair (2d, 2d+1):  k = kt*32 + (lane>>4)*8 + 2d+c, n(j) = nt*16 + (lane&15)
//   [8192, 8448): L1 per k: float4 (W1[k][0], W1[k][1], W1[k][2], b1[k])
//   [8448, 8576): C2 per j: float2 (W2[j][0], b2[j])
//   [8576, 8704): L3 per j: float2 (W3[0][j+1], W3[1][j+1])
//   [8704, 8708): C3: (W3[0][0], W3[1][0], b3[0], b3[1])

__global__ void ffjord_prep(const float* __restrict__ W1, const float* __restrict__ b1,
                            const float* __restrict__ W2, const float* __restrict__ b2,
                            const float* __restrict__ W3, const float* __restrict__ b3,
                            float* __restrict__ ws) {
  int tid = threadIdx.x;  // single block, 256 threads
  uint* wsu = (uint*)ws;
  for (int e2 = tid; e2 < 8192; e2 += 256) {
    int mat = e2 >> 11;
    int rem = e2 & 2047;
    int fr  = rem >> 8;          // kt*4+nt
    int l   = (rem >> 2) & 63;
    int d   = rem & 3;
    int kt = fr >> 2, nt = fr & 3;
    int g = l >> 4, cc = l & 15;
    int k0 = kt * 32 + g * 8 + 2 * d;
    int j  = nt * 16 + cc;
    float v0, v1;
    if (mat < 2) {
      v0 = W2[j * 65 + k0 + 1];
      v1 = W2[j * 65 + k0 + 2];
    } else {
      float p0 = W1[k0 * 3 + 1] * W3[j + 1] + W1[k0 * 3 + 2] * W3[65 + j + 1];
      float p1 = W1[(k0 + 1) * 3 + 1] * W3[j + 1] + W1[(k0 + 1) * 3 + 2] * W3[65 + j + 1];
      v0 = p0 * W2[j * 65 + k0 + 1];
      v1 = p1 * W2[j * 65 + k0 + 2];
    }
    unsigned short h0 = rne_bf16u(v0), h1 = rne_bf16u(v1);
    if (mat & 1) {  // lo plane = bf16 of residual
      h0 = rne_bf16u(v0 - bf16f(rne_bf16u(v0)));
      h1 = rne_bf16u(v1 - bf16f(rne_bf16u(v1)));
    }
    wsu[e2] = (uint)h0 | ((uint)h1 << 16);
  }
  if (tid < HDIM) {
    ws[8192 + tid * 4 + 0] = W1[tid * 3 + 0];
    ws[8192 + tid * 4 + 1] = W1[tid * 3 + 1];
    ws[8192 + tid * 4 + 2] = W1[tid * 3 + 2];
    ws[8192 + tid * 4 + 3] = b1[tid];
    ws[8448 + tid * 2 + 0] = W2[tid * 65 + 0];
    ws[8448 + tid * 2 + 1] = b2[tid];
    ws[8576 + tid * 2 + 0] = W3[tid + 1];
    ws[8576 + tid * 2 + 1] = W3[65 + tid + 1];
  }
  if (tid == 0) {
    ws[8704] = W3[0];
    ws[8705] = W3[65];
    ws[8706] = b3[0];
    ws[8707] = b3[1];
  }
}

// Per wave = 64 points; both matvecs as 64x64x64 GEMMs (mfma_f32_16x16x32_bf16,
// 3-term bf16 hi/lo split — validated r8, absmax 0.0156). r8's failure was
// register spill (2.6 GB scratch: whole-eval live set ~180 regs vs 64-reg
// clamp). Fix: mt-local pipeline — per output row-tile mt, build SP+SG A-frags
// from ONE a_k chain, GEMM1 row, activations/g row, GEMM2 row + dv partial,
// all transient. Peak live ~95 regs under the (256,2) 128 cap. B-frags/L1
// re-read from LDS per mt (mt-invariant loads pinned in-loop by a memory
// clobber so LICM can't rebuild r8's live set). redLds shrunk via full
// shfl-xor reduce -> 39.9 KB LDS -> 4 blocks/CU. Zero main-loop barriers.
__global__ __launch_bounds__(256, 2) void ffjord_main(
    const float* __restrict__ z_in, const float* __restrict__ dlp_in,
    const float* __restrict__ ws, float* __restrict__ out, int B) {
  __shared__ uint4 fragLds[2048];        // 32 KB: 4 planes x 512 uint4
  __shared__ float4 l1Lds[64];           // 1 KB
  __shared__ float2 c2Lds[64];           // 512 B
  __shared__ float2 l3Lds[64];           // 512 B
  __shared__ float2 stateLds[4][64];     // 2 KB  (per-wave zt broadcast)
  __shared__ float  redLds[4][3][64];    // 3 KB  (per-wave zd0/zd1/dv, fully reduced)

  int tid = threadIdx.x;
  const uint4* wsu4 = (const uint4*)ws;
  #pragma unroll
  for (int j = 0; j < 8; ++j) fragLds[tid + 256 * j] = wsu4[tid + 256 * j];
  if (tid < 64) {
    l1Lds[tid] = ((const float4*)(ws + 8192))[tid];
    c2Lds[tid] = ((const float2*)(ws + 8448))[tid];
    l3Lds[tid] = ((const float2*)(ws + 8576))[tid];
  }
  __syncthreads();

  const float c30 = ws[8704], c31 = ws[8705], cb0 = ws[8706], cb1 = ws[8707];

  int wid = tid >> 6, l = tid & 63;
  int g = l >> 4, c = l & 15;
  int pt = blockIdx.x * 256 + wid * 64 + l;
  int ptc = pt < B ? pt : (B - 1);

  float z0 = z_in[2 * ptc], z1 = z_in[2 * ptc + 1];
  float lp = dlp_in[ptc];
  const float dt = 1.0f / NSTEPS;

  #pragma unroll 1
  for (int step = 0; step < NSTEPS; ++step) {
    float t0 = step * dt;
    float az0 = 0.f, az1 = 0.f, al = 0.f;
    float zt0 = z0, zt1 = z1, ts = t0;

    #pragma unroll 1
    for (int s = 0; s < 4; ++s) {
      // publish zt for this wave's 64 points
      stateLds[wid][l] = make_float2(zt0, zt1);
      float c2n[4];
      #pragma unroll
      for (int nt = 0; nt < 4; ++nt) {
        float2 cc = c2Lds[nt * 16 + c];
        c2n[nt] = fmaf(cc.x, ts, cc.y);
      }

      #pragma unroll 1
      for (int mt = 0; mt < 4; ++mt) {
        asm volatile("" ::: "memory");  // pin mt-invariant LDS loads inside the loop
        float2 sv = stateLds[wid][mt * 16 + c];
        float mz0 = sv.x, mz1 = sv.y;

        // ---- A-frags for row-tile mt: softplus (SP) and sigmoid (SG), hi/lo ----
        FragU SPh[2], SPl[2], SGh[2], SGl[2];
        #pragma unroll
        for (int kt = 0; kt < 2; ++kt) {
          float sp[8], sg[8];
          #pragma unroll
          for (int e = 0; e < 8; ++e) {
            float4 par = l1Lds[kt * 32 + g * 8 + e];
            float a = fmaf(par.x, ts, fmaf(par.y, mz0, fmaf(par.z, mz1, par.w)));
            float ex = __expf(-fabsf(a));
            float rc = __builtin_amdgcn_rcpf(1.0f + ex);
            sg[e] = (a >= 0.f ? 1.0f : ex) * rc;           // sigmoid(a)
            sp[e] = fmaxf(a, 0.f) + __logf(1.0f + ex);     // softplus(a)
          }
          #pragma unroll
          for (int d = 0; d < 4; ++d) {
            uint hp = cvt_pk_bf16(sp[2 * d], sp[2 * d + 1]);
            SPh[kt].u[d] = hp;
            SPl[kt].u[d] = cvt_pk_bf16(sp[2 * d] - lo_bf16_f32(hp),
                                       sp[2 * d + 1] - hi_bf16_f32(hp));
            uint hg = cvt_pk_bf16(sg[2 * d], sg[2 * d + 1]);
            SGh[kt].u[d] = hg;
            SGl[kt].u[d] = cvt_pk_bf16(sg[2 * d] - lo_bf16_f32(hg),
                                       sg[2 * d + 1] - hi_bf16_f32(hg));
          }
        }

        // ---- GEMM1 row: H2[mt][:] = SP * W2T ----
        f32x4 C1r[4];
        #pragma unroll
        for (int nt = 0; nt < 4; ++nt) C1r[nt] = (f32x4){0.f, 0.f, 0.f, 0.f};
        #pragma unroll
        for (int kt = 0; kt < 2; ++kt) {
          #pragma unroll
          for (int nt = 0; nt < 4; ++nt) {
            FragU Bh, Bl;
            Bh.u4 = fragLds[(kt * 4 + nt) * 64 + l];
            Bl.u4 = fragLds[512 + (kt * 4 + nt) * 64 + l];
            C1r[nt] = __builtin_amdgcn_mfma_f32_16x16x32_bf16(SPh[kt].v, Bh.v, C1r[nt], 0, 0, 0);
            C1r[nt] = __builtin_amdgcn_mfma_f32_16x16x32_bf16(SPh[kt].v, Bl.v, C1r[nt], 0, 0, 0);
            C1r[nt] = __builtin_amdgcn_mfma_f32_16x16x32_bf16(SPl[kt].v, Bh.v, C1r[nt], 0, 0, 0);
          }
        }

        // ---- mid: zd partials, g = sigmoid(h2) kept f32 ----
        float zp0[4] = {0.f, 0.f, 0.f, 0.f}, zp1[4] = {0.f, 0.f, 0.f, 0.f};
        float gmat[4][4];
        #pragma unroll
        for (int nt = 0; nt < 4; ++nt) {
          float2 l3 = l3Lds[nt * 16 + c];
          #pragma unroll
          for (int r = 0; r < 4; ++r) {
            float h2 = C1r[nt][r] + c2n[nt];
            float ex = __expf(-fabsf(h2));
            float rc = __builtin_amdgcn_rcpf(1.0f + ex);
            gmat[nt][r] = (h2 >= 0.f ? 1.0f : ex) * rc;    // sigmoid
            float sq = fmaxf(h2, 0.f) + __logf(1.0f + ex); // softplus
            zp0[r] = fmaf(l3.x, sq, zp0[r]);
            zp1[r] = fmaf(l3.y, sq, zp1[r]);
          }
        }
        #pragma unroll
        for (int r = 0; r < 4; ++r) {
          zp0[r] += __shfl_xor(zp0[r], 1); zp0[r] += __shfl_xor(zp0[r], 2);
          zp0[r] += __shfl_xor(zp0[r], 4); zp0[r] += __shfl_xor(zp0[r], 8);
          zp1[r] += __shfl_xor(zp1[r], 1); zp1[r] += __shfl_xor(zp1[r], 2);
          zp1[r] += __shfl_xor(zp1[r], 4); zp1[r] += __shfl_xor(zp1[r], 8);
        }
        if (c == 0) {
          #pragma unroll
          for (int r = 0; r < 4; ++r) {
            redLds[wid][0][mt * 16 + g * 4 + r] = zp0[r];
            redLds[wid][1][mt * 16 + g * 4 + r] = zp1[r];
          }
        }

        // ---- GEMM2 row: R[mt][:] = SG * QT, dv row += R .* g ----
        float dvp[4] = {0.f, 0.f, 0.f, 0.f};
        #pragma unroll
        for (int nt = 0; nt < 4; ++nt) {
          f32x4 C2r = (f32x4){0.f, 0.f, 0.f, 0.f};
          #pragma unroll
          for (int kt = 0; kt < 2; ++kt) {
            FragU Bh, Bl;
            Bh.u4 = fragLds[1024 + (kt * 4 + nt) * 64 + l];
            Bl.u4 = fragLds[1536 + (kt * 4 + nt) * 64 + l];
            C2r = __builtin_amdgcn_mfma_f32_16x16x32_bf16(SGh[kt].v, Bh.v, C2r, 0, 0, 0);
            C2r = __builtin_amdgcn_mfma_f32_16x16x32_bf16(SGh[kt].v, Bl.v, C2r, 0, 0, 0);
            C2r = __builtin_amdgcn_mfma_f32_16x16x32_bf16(SGl[kt].v, Bh.v, C2r, 0, 0, 0);
          }
          #pragma unroll
          for (int r = 0; r < 4; ++r)
            dvp[r] = fmaf(C2r[r], gmat[nt][r], dvp[r]);
        }
        #pragma unroll
        for (int r = 0; r < 4; ++r) {
          dvp[r] += __shfl_xor(dvp[r], 1); dvp[r] += __shfl_xor(dvp[r], 2);
          dvp[r] += __shfl_xor(dvp[r], 4); dvp[r] += __shfl_xor(dvp[r], 8);
        }
        if (c == 0) {
          #pragma unroll
          for (int r = 0; r < 4; ++r)
            redLds[wid][2][mt * 16 + g * 4 + r] = dvp[r];
        }
      }

      // ---- owner: collect zd/dv, RK4 ----
      float zd0 = redLds[wid][0][l] + fmaf(c30, ts, cb0);
      float zd1 = redLds[wid][1][l] + fmaf(c31, ts, cb1);
      float dv  = redLds[wid][2][l];

      float w = (s == 1 || s == 2) ? 2.0f : 1.0f;
      az0 = fmaf(w, zd0, az0);
      az1 = fmaf(w, zd1, az1);
      al  = fmaf(w, dv, al);
      if (s < 3) {
        float cc2 = (s == 2) ? dt : 0.5f * dt;
        zt0 = fmaf(cc2, zd0, z0);
        zt1 = fmaf(cc2, zd1, z1);
        ts = t0 + cc2;
      }
    }
    z0 = fmaf(dt / 6.0f, az0, z0);
    z1 = fmaf(dt / 6.0f, az1, z1);
    lp = fmaf(-dt / 6.0f, al, lp);  // k_l = -div
  }

  if (pt < B) {
    out[2 * pt] = z0;
    out[2 * pt + 1] = z1;
    out[2 * B + pt] = lp;
  }
}

extern "C" void kernel_launch(void* const* d_in, const int* in_sizes, int n_in,
                              void* d_out, int out_size, void* d_ws, size_t ws_size,
                              hipStream_t stream) {
  const float* z   = (const float*)d_in[0];
  const float* dlp = (const float*)d_in[1];
  const float* W1  = (const float*)d_in[2];
  const float* b1  = (const float*)d_in[3];
  const float* W2  = (const float*)d_in[4];
  const float* b2  = (const float*)d_in[5];
  const float* W3  = (const float*)d_in[6];
  const float* b3  = (const float*)d_in[7];
  float* out = (float*)d_out;
  float* ws = (float*)d_ws;

  int B = in_sizes[0] / 2;

  ffjord_prep<<<1, 256, 0, stream>>>(W1, b1, W2, b2, W3, b3, ws);
  int blocks = (B + 255) / 256;  // 256 points per block, 64 per wave
  ffjord_main<<<blocks, 256, 0, stream>>>(z, dlp, ws, out, B);
}

// Round 10
// 609.690 us; speedup vs baseline: 2.5685x; 1.0457x over previous
//
#include <hip/hip_runtime.h>

#define HDIM 64
#define NSTEPS 4

typedef __attribute__((ext_vector_type(4))) float f32x4;
typedef __attribute__((ext_vector_type(8))) short bf16x8;
typedef unsigned int uint;

union FragU { uint u[4]; uint4 u4; bf16x8 v; };

__device__ inline uint cvt_pk_bf16(float a, float b) {
  uint d;
  asm("v_cvt_pk_bf16_f32 %0, %1, %2" : "=v"(d) : "v"(a), "v"(b));
  return d;  // low16 = bf16(a), high16 = bf16(b), RNE
}
__device__ inline float lo_bf16_f32(uint p) { return __builtin_bit_cast(float, p << 16); }
__device__ inline float hi_bf16_f32(uint p) { return __builtin_bit_cast(float, p & 0xFFFF0000u); }

__device__ inline unsigned short rne_bf16u(float x) {
  uint u = __builtin_bit_cast(uint, x);
  uint r = u + 0x7FFFu + ((u >> 16) & 1u);
  return (unsigned short)(r >> 16);
}
__device__ inline float bf16f(unsigned short h) { return __builtin_bit_cast(float, ((uint)h) << 16); }

// Sum over the 16 lanes of a DPP row (our c-index) via rotate-reduce:
// x += ror8(x); x += ror4(x); x += ror2(x); x += ror1(x). Pure VALU — replaces
// the 4-deep shfl_xor/LDS-pipe chains of r9. All 4 rows of the wave reduce
// independently (= the 4 g-groups), which is exactly what we need.
__device__ inline float row_sum16(float x) {
  int v = __builtin_bit_cast(int, x);
  x += __builtin_bit_cast(float, __builtin_amdgcn_update_dpp(0, v, 0x128, 0xF, 0xF, true));
  v = __builtin_bit_cast(int, x);
  x += __builtin_bit_cast(float, __builtin_amdgcn_update_dpp(0, v, 0x124, 0xF, 0xF, true));
  v = __builtin_bit_cast(int, x);
  x += __builtin_bit_cast(float, __builtin_amdgcn_update_dpp(0, v, 0x122, 0xF, 0xF, true));
  v = __builtin_bit_cast(int, x);
  x += __builtin_bit_cast(float, __builtin_amdgcn_update_dpp(0, v, 0x121, 0xF, 0xF, true));
  return x;
}

__device__ inline void pack_hilo(const float* x, FragU& H, FragU& L) {
  #pragma unroll
  for (int d = 0; d < 4; ++d) {
    uint h = cvt_pk_bf16(x[2 * d], x[2 * d + 1]);
    H.u[d] = h;
    L.u[d] = cvt_pk_bf16(x[2 * d] - lo_bf16_f32(h), x[2 * d + 1] - hi_bf16_f32(h));
  }
}

// ws layout (dword offsets) — identical to rounds 8/9:
//   [0,    8192): fragment planes, 2048 dw each:
//       mat0 = W2T hi, mat1 = W2T lo, mat2 = QT hi, mat3 = QT lo
//     dword index within plane: ((kt*4+nt)*64 + lane)*4 + d
//     element pair (2d, 2d+1):  k = kt*32 + (lane>>4)*8 + 2d+c, n(j) = nt*16 + (lane&15)
//   [8192, 8448): L1 per k: float4 (W1[k][0], W1[k][1], W1[k][2], b1[k])
//   [8448, 8576): C2 per j: float2 (W2[j][0], b2[j])
//   [8576, 8704): L3 per j: float2 (W3[0][j+1], W3[1][j+1])
//   [8704, 8708): C3: (W3[0][0], W3[1][0], b3[0], b3[1])

__global__ void ffjord_prep(const float* __restrict__ W1, const float* __restrict__ b1,
                            const float* __restrict__ W2, const float* __restrict__ b2,
                            const float* __restrict__ W3, const float* __restrict__ b3,
                            float* __restrict__ ws) {
  int tid = threadIdx.x;  // single block, 256 threads
  uint* wsu = (uint*)ws;
  for (int e2 = tid; e2 < 8192; e2 += 256) {
    int mat = e2 >> 11;
    int rem = e2 & 2047;
    int fr  = rem >> 8;          // kt*4+nt
    int l   = (rem >> 2) & 63;
    int d   = rem & 3;
    int kt = fr >> 2, nt = fr & 3;
    int g = l >> 4, cc = l & 15;
    int k0 = kt * 32 + g * 8 + 2 * d;
    int j  = nt * 16 + cc;
    float v0, v1;
    if (mat < 2) {
      v0 = W2[j * 65 + k0 + 1];
      v1 = W2[j * 65 + k0 + 2];
    } else {
      float p0 = W1[k0 * 3 + 1] * W3[j + 1] + W1[k0 * 3 + 2] * W3[65 + j + 1];
      float p1 = W1[(k0 + 1) * 3 + 1] * W3[j + 1] + W1[(k0 + 1) * 3 + 2] * W3[65 + j + 1];
      v0 = p0 * W2[j * 65 + k0 + 1];
      v1 = p1 * W2[j * 65 + k0 + 2];
    }
    unsigned short h0 = rne_bf16u(v0), h1 = rne_bf16u(v1);
    if (mat & 1) {  // lo plane = bf16 of residual
      h0 = rne_bf16u(v0 - bf16f(rne_bf16u(v0)));
      h1 = rne_bf16u(v1 - bf16f(rne_bf16u(v1)));
    }
    wsu[e2] = (uint)h0 | ((uint)h1 << 16);
  }
  if (tid < HDIM) {
    ws[8192 + tid * 4 + 0] = W1[tid * 3 + 0];
    ws[8192 + tid * 4 + 1] = W1[tid * 3 + 1];
    ws[8192 + tid * 4 + 2] = W1[tid * 3 + 2];
    ws[8192 + tid * 4 + 3] = b1[tid];
    ws[8448 + tid * 2 + 0] = W2[tid * 65 + 0];
    ws[8448 + tid * 2 + 1] = b2[tid];
    ws[8576 + tid * 2 + 0] = W3[tid + 1];
    ws[8576 + tid * 2 + 1] = W3[65 + tid + 1];
  }
  if (tid == 0) {
    ws[8704] = W3[0];
    ws[8705] = W3[65];
    ws[8706] = b3[0];
    ws[8707] = b3[1];
  }
}

// r9 structure (mt-local pipeline, validated absmax 0.031, zero spill) with two
// ILP upgrades: (1) mt-tiles processed in PAIRS — two independent dependency
// spines interleave, and the mt-invariant B-fragment / L1 LDS reads are shared
// (ds_read traffic halves); (2) cross-lane reduce via DPP row_ror rotate-
// reduce (pure VALU) instead of shfl_xor LDS round trips. Numerics unchanged:
// 3-term bf16 hi/lo split on BOTH GEMMs. Pair live set ~105 regs < (256,2)'s
// 128 cap. Checkpoint: WRITE_SIZE must stay ~3 MB.
__global__ __launch_bounds__(256, 2) void ffjord_main(
    const float* __restrict__ z_in, const float* __restrict__ dlp_in,
    const float* __restrict__ ws, float* __restrict__ out, int B) {
  __shared__ uint4 fragLds[2048];        // 32 KB
  __shared__ float4 l1Lds[64];           // 1 KB
  __shared__ float2 c2Lds[64];           // 512 B
  __shared__ float2 l3Lds[64];           // 512 B
  __shared__ float2 stateLds[4][64];     // 2 KB
  __shared__ float  redLds[4][3][64];    // 3 KB

  int tid = threadIdx.x;
  const uint4* wsu4 = (const uint4*)ws;
  #pragma unroll
  for (int j = 0; j < 8; ++j) fragLds[tid + 256 * j] = wsu4[tid + 256 * j];
  if (tid < 64) {
    l1Lds[tid] = ((const float4*)(ws + 8192))[tid];
    c2Lds[tid] = ((const float2*)(ws + 8448))[tid];
    l3Lds[tid] = ((const float2*)(ws + 8576))[tid];
  }
  __syncthreads();

  const float c30 = ws[8704], c31 = ws[8705], cb0 = ws[8706], cb1 = ws[8707];

  int wid = tid >> 6, l = tid & 63;
  int g = l >> 4, c = l & 15;
  int pt = blockIdx.x * 256 + wid * 64 + l;
  int ptc = pt < B ? pt : (B - 1);

  float z0 = z_in[2 * ptc], z1 = z_in[2 * ptc + 1];
  float lp = dlp_in[ptc];
  const float dt = 1.0f / NSTEPS;

  #pragma unroll 1
  for (int step = 0; step < NSTEPS; ++step) {
    float t0 = step * dt;
    float az0 = 0.f, az1 = 0.f, al = 0.f;
    float zt0 = z0, zt1 = z1, ts = t0;

    #pragma unroll 1
    for (int s = 0; s < 4; ++s) {
      stateLds[wid][l] = make_float2(zt0, zt1);
      float c2n[4];
      #pragma unroll
      for (int nt = 0; nt < 4; ++nt) {
        float2 cc = c2Lds[nt * 16 + c];
        c2n[nt] = fmaf(cc.x, ts, cc.y);
      }

      #pragma unroll 1
      for (int p = 0; p < 2; ++p) {
        asm volatile("" ::: "memory");  // pin pair-invariant LDS loads per pair
        int mtA = 2 * p, mtB = 2 * p + 1;
        float2 svA = stateLds[wid][mtA * 16 + c];
        float2 svB = stateLds[wid][mtB * 16 + c];

        // ---- A-frags for both row-tiles (one a_k chain each, SP+SG) ----
        FragU SPhA[2], SPlA[2], SGhA[2], SGlA[2];
        FragU SPhB[2], SPlB[2], SGhB[2], SGlB[2];
        #pragma unroll
        for (int kt = 0; kt < 2; ++kt) {
          float spA[8], sgA[8], spB[8], sgB[8];
          #pragma unroll
          for (int e = 0; e < 8; ++e) {
            float4 par = l1Lds[kt * 32 + g * 8 + e];  // shared by A and B
            float base = fmaf(par.x, ts, par.w);
            {
              float a = fmaf(par.y, svA.x, fmaf(par.z, svA.y, base));
              float ex = __expf(-fabsf(a));
              float rc = __builtin_amdgcn_rcpf(1.0f + ex);
              sgA[e] = (a >= 0.f ? 1.0f : ex) * rc;
              spA[e] = fmaxf(a, 0.f) + __logf(1.0f + ex);
            }
            {
              float a = fmaf(par.y, svB.x, fmaf(par.z, svB.y, base));
              float ex = __expf(-fabsf(a));
              float rc = __builtin_amdgcn_rcpf(1.0f + ex);
              sgB[e] = (a >= 0.f ? 1.0f : ex) * rc;
              spB[e] = fmaxf(a, 0.f) + __logf(1.0f + ex);
            }
          }
          pack_hilo(spA, SPhA[kt], SPlA[kt]);
          pack_hilo(sgA, SGhA[kt], SGlA[kt]);
          pack_hilo(spB, SPhB[kt], SPlB[kt]);
          pack_hilo(sgB, SGhB[kt], SGlB[kt]);
        }

        // ---- GEMM1 both rows, shared B reads ----
        f32x4 C1A[4], C1B[4];
        #pragma unroll
        for (int nt = 0; nt < 4; ++nt) {
          C1A[nt] = (f32x4){0.f, 0.f, 0.f, 0.f};
          C1B[nt] = (f32x4){0.f, 0.f, 0.f, 0.f};
        }
        #pragma unroll
        for (int kt = 0; kt < 2; ++kt) {
          #pragma unroll
          for (int nt = 0; nt < 4; ++nt) {
            FragU Bh, Bl;
            Bh.u4 = fragLds[(kt * 4 + nt) * 64 + l];
            Bl.u4 = fragLds[512 + (kt * 4 + nt) * 64 + l];
            C1A[nt] = __builtin_amdgcn_mfma_f32_16x16x32_bf16(SPhA[kt].v, Bh.v, C1A[nt], 0, 0, 0);
            C1B[nt] = __builtin_amdgcn_mfma_f32_16x16x32_bf16(SPhB[kt].v, Bh.v, C1B[nt], 0, 0, 0);
            C1A[nt] = __builtin_amdgcn_mfma_f32_16x16x32_bf16(SPhA[kt].v, Bl.v, C1A[nt], 0, 0, 0);
            C1B[nt] = __builtin_amdgcn_mfma_f32_16x16x32_bf16(SPhB[kt].v, Bl.v, C1B[nt], 0, 0, 0);
            C1A[nt] = __builtin_amdgcn_mfma_f32_16x16x32_bf16(SPlA[kt].v, Bh.v, C1A[nt], 0, 0, 0);
            C1B[nt] = __builtin_amdgcn_mfma_f32_16x16x32_bf16(SPlB[kt].v, Bh.v, C1B[nt], 0, 0, 0);
          }
        }

        // ---- mid both: zd partials, g = sigmoid(h2) f32 ----
        float zp0A[4] = {0.f, 0.f, 0.f, 0.f}, zp1A[4] = {0.f, 0.f, 0.f, 0.f};
        float zp0B[4] = {0.f, 0.f, 0.f, 0.f}, zp1B[4] = {0.f, 0.f, 0.f, 0.f};
        float gA[4][4], gB[4][4];
        #pragma unroll
        for (int nt = 0; nt < 4; ++nt) {
          float2 l3 = l3Lds[nt * 16 + c];
          #pragma unroll
          for (int r = 0; r < 4; ++r) {
            {
              float h2 = C1A[nt][r] + c2n[nt];
              float ex = __expf(-fabsf(h2));
              float rc = __builtin_amdgcn_rcpf(1.0f + ex);
              gA[nt][r] = (h2 >= 0.f ? 1.0f : ex) * rc;
              float sq = fmaxf(h2, 0.f) + __logf(1.0f + ex);
              zp0A[r] = fmaf(l3.x, sq, zp0A[r]);
              zp1A[r] = fmaf(l3.y, sq, zp1A[r]);
            }
            {
              float h2 = C1B[nt][r] + c2n[nt];
              float ex = __expf(-fabsf(h2));
              float rc = __builtin_amdgcn_rcpf(1.0f + ex);
              gB[nt][r] = (h2 >= 0.f ? 1.0f : ex) * rc;
              float sq = fmaxf(h2, 0.f) + __logf(1.0f + ex);
              zp0B[r] = fmaf(l3.x, sq, zp0B[r]);
              zp1B[r] = fmaf(l3.y, sq, zp1B[r]);
            }
          }
        }
        #pragma unroll
        for (int r = 0; r < 4; ++r) {
          zp0A[r] = row_sum16(zp0A[r]); zp1A[r] = row_sum16(zp1A[r]);
          zp0B[r] = row_sum16(zp0B[r]); zp1B[r] = row_sum16(zp1B[r]);
        }
        if (c == 0) {
          #pragma unroll
          for (int r = 0; r < 4; ++r) {
            redLds[wid][0][mtA * 16 + g * 4 + r] = zp0A[r];
            redLds[wid][1][mtA * 16 + g * 4 + r] = zp1A[r];
            redLds[wid][0][mtB * 16 + g * 4 + r] = zp0B[r];
            redLds[wid][1][mtB * 16 + g * 4 + r] = zp1B[r];
          }
        }

        // ---- GEMM2 both rows, shared B reads; dv += R .* g ----
        float dvA[4] = {0.f, 0.f, 0.f, 0.f}, dvB[4] = {0.f, 0.f, 0.f, 0.f};
        #pragma unroll
        for (int nt = 0; nt < 4; ++nt) {
          f32x4 C2A = (f32x4){0.f, 0.f, 0.f, 0.f};
          f32x4 C2B = (f32x4){0.f, 0.f, 0.f, 0.f};
          #pragma unroll
          for (int kt = 0; kt < 2; ++kt) {
            FragU Bh, Bl;
            Bh.u4 = fragLds[1024 + (kt * 4 + nt) * 64 + l];
            Bl.u4 = fragLds[1536 + (kt * 4 + nt) * 64 + l];
            C2A = __builtin_amdgcn_mfma_f32_16x16x32_bf16(SGhA[kt].v, Bh.v, C2A, 0, 0, 0);
            C2B = __builtin_amdgcn_mfma_f32_16x16x32_bf16(SGhB[kt].v, Bh.v, C2B, 0, 0, 0);
            C2A = __builtin_amdgcn_mfma_f32_16x16x32_bf16(SGhA[kt].v, Bl.v, C2A, 0, 0, 0);
            C2B = __builtin_amdgcn_mfma_f32_16x16x32_bf16(SGhB[kt].v, Bl.v, C2B, 0, 0, 0);
            C2A = __builtin_amdgcn_mfma_f32_16x16x32_bf16(SGlA[kt].v, Bh.v, C2A, 0, 0, 0);
            C2B = __builtin_amdgcn_mfma_f32_16x16x32_bf16(SGlB[kt].v, Bh.v, C2B, 0, 0, 0);
          }
          #pragma unroll
          for (int r = 0; r < 4; ++r) {
            dvA[r] = fmaf(C2A[r], gA[nt][r], dvA[r]);
            dvB[r] = fmaf(C2B[r], gB[nt][r], dvB[r]);
          }
        }
        #pragma unroll
        for (int r = 0; r < 4; ++r) {
          dvA[r] = row_sum16(dvA[r]);
          dvB[r] = row_sum16(dvB[r]);
        }
        if (c == 0) {
          #pragma unroll
          for (int r = 0; r < 4; ++r) {
            redLds[wid][2][mtA * 16 + g * 4 + r] = dvA[r];
            redLds[wid][2][mtB * 16 + g * 4 + r] = dvB[r];
          }
        }
      }

      // ---- owner: collect zd/dv, RK4 ----
      float zd0 = redLds[wid][0][l] + fmaf(c30, ts, cb0);
      float zd1 = redLds[wid][1][l] + fmaf(c31, ts, cb1);
      float dv  = redLds[wid][2][l];

      float w = (s == 1 || s == 2) ? 2.0f : 1.0f;
      az0 = fmaf(w, zd0, az0);
      az1 = fmaf(w, zd1, az1);
      al  = fmaf(w, dv, al);
      if (s < 3) {
        float cc2 = (s == 2) ? dt : 0.5f * dt;
        zt0 = fmaf(cc2, zd0, z0);
        zt1 = fmaf(cc2, zd1, z1);
        ts = t0 + cc2;
      }
    }
    z0 = fmaf(dt / 6.0f, az0, z0);
    z1 = fmaf(dt / 6.0f, az1, z1);
    lp = fmaf(-dt / 6.0f, al, lp);  // k_l = -div
  }

  if (pt < B) {
    out[2 * pt] = z0;
    out[2 * pt + 1] = z1;
    out[2 * B + pt] = lp;
  }
}

extern "C" void kernel_launch(void* const* d_in, const int* in_sizes, int n_in,
                              void* d_out, int out_size, void* d_ws, size_t ws_size,
                              hipStream_t stream) {
  const float* z   = (const float*)d_in[0];
  const float* dlp = (const float*)d_in[1];
  const float* W1  = (const float*)d_in[2];
  const float* b1  = (const float*)d_in[3];
  const float* W2  = (const float*)d_in[4];
  const float* b2  = (const float*)d_in[5];
  const float* W3  = (const float*)d_in[6];
  const float* b3  = (const float*)d_in[7];
  float* out = (float*)d_out;
  float* ws = (float*)d_ws;

  int B = in_sizes[0] / 2;

  ffjord_prep<<<1, 256, 0, stream>>>(W1, b1, W2, b2, W3, b3, ws);
  int blocks = (B + 255) / 256;  // 256 points per block, 64 per wave
  ffjord_main<<<blocks, 256, 0, stream>>>(z, dlp, ws, out, B);
}

// Round 11
// 601.702 us; speedup vs baseline: 2.6026x; 1.0133x over previous
//
#include <hip/hip_runtime.h>

#define HDIM 64
#define NSTEPS 4

typedef __attribute__((ext_vector_type(4))) float f32x4;
typedef __attribute__((ext_vector_type(8))) short bf16x8;
typedef unsigned int uint;

union FragU { uint u[4]; uint4 u4; bf16x8 v; };

__device__ inline uint cvt_pk_bf16(float a, float b) {
  uint d;
  asm("v_cvt_pk_bf16_f32 %0, %1, %2" : "=v"(d) : "v"(a), "v"(b));
  return d;  // low16 = bf16(a), high16 = bf16(b), RNE
}
__device__ inline float lo_bf16_f32(uint p) { return __builtin_bit_cast(float, p << 16); }
__device__ inline float hi_bf16_f32(uint p) { return __builtin_bit_cast(float, p & 0xFFFF0000u); }

__device__ inline unsigned short rne_bf16u(float x) {
  uint u = __builtin_bit_cast(uint, x);
  uint r = u + 0x7FFFu + ((u >> 16) & 1u);
  return (unsigned short)(r >> 16);
}
__device__ inline float bf16f(unsigned short h) { return __builtin_bit_cast(float, ((uint)h) << 16); }

// Sum over the 16 lanes of a DPP row via rotate-reduce (pure VALU; result in
// every lane of the row).
__device__ inline float row_sum16(float x) {
  int v = __builtin_bit_cast(int, x);
  x += __builtin_bit_cast(float, __builtin_amdgcn_update_dpp(0, v, 0x128, 0xF, 0xF, true));
  v = __builtin_bit_cast(int, x);
  x += __builtin_bit_cast(float, __builtin_amdgcn_update_dpp(0, v, 0x124, 0xF, 0xF, true));
  v = __builtin_bit_cast(int, x);
  x += __builtin_bit_cast(float, __builtin_amdgcn_update_dpp(0, v, 0x122, 0xF, 0xF, true));
  v = __builtin_bit_cast(int, x);
  x += __builtin_bit_cast(float, __builtin_amdgcn_update_dpp(0, v, 0x121, 0xF, 0xF, true));
  return x;
}

// Pack a value pair to bf16 hi-plane + residual lo-plane dwords.
__device__ inline void pack2(float x0, float x1, uint& H, uint& L) {
  uint h = cvt_pk_bf16(x0, x1);
  H = h;
  L = cvt_pk_bf16(x0 - lo_bf16_f32(h), x1 - hi_bf16_f32(h));
}

// Layer-1 activation chain: a = par.(t,z) -> softplus(a), sigmoid(a).
__device__ inline void l1chain(float4 par, float base, float s0, float s1,
                               float& sp, float& sg) {
  float a = fmaf(par.y, s0, fmaf(par.z, s1, base));
  float ex = __expf(-fabsf(a));
  float rc = __builtin_amdgcn_rcpf(1.0f + ex);
  sg = (a >= 0.f ? 1.0f : ex) * rc;
  sp = fmaxf(a, 0.f) + __logf(1.0f + ex);
}

// ws layout (dword offsets) — identical to rounds 8-10:
//   [0,    8192): fragment planes, 2048 dw each:
//       mat0 = W2T hi, mat1 = W2T lo, mat2 = QT hi, mat3 = QT lo
//     dword index within plane: ((kt*4+nt)*64 + lane)*4 + d
//     element pair (2d, 2d+1):  k = kt*32 + (lane>>4)*8 + 2d(+1), n(j) = nt*16 + (lane&15)
//   [8192, 8448): L1 per k: float4 (W1[k][0], W1[k][1], W1[k][2], b1[k])
//   [8448, 8576): C2 per j: float2 (W2[j][0], b2[j])
//   [8576, 8704): L3 per j: float2 (W3[0][j+1], W3[1][j+1])
//   [8704, 8708): C3: (W3[0][0], W3[1][0], b3[0], b3[1])

__global__ void ffjord_prep(const float* __restrict__ W1, const float* __restrict__ b1,
                            const float* __restrict__ W2, const float* __restrict__ b2,
                            const float* __restrict__ W3, const float* __restrict__ b3,
                            float* __restrict__ ws) {
  int tid = threadIdx.x;  // single block, 256 threads
  uint* wsu = (uint*)ws;
  for (int e2 = tid; e2 < 8192; e2 += 256) {
    int mat = e2 >> 11;
    int rem = e2 & 2047;
    int fr  = rem >> 8;          // kt*4+nt
    int l   = (rem >> 2) & 63;
    int d   = rem & 3;
    int kt = fr >> 2, nt = fr & 3;
    int g = l >> 4, cc = l & 15;
    int k0 = kt * 32 + g * 8 + 2 * d;
    int j  = nt * 16 + cc;
    float v0, v1;
    if (mat < 2) {
      v0 = W2[j * 65 + k0 + 1];
      v1 = W2[j * 65 + k0 + 2];
    } else {
      float p0 = W1[k0 * 3 + 1] * W3[j + 1] + W1[k0 * 3 + 2] * W3[65 + j + 1];
      float p1 = W1[(k0 + 1) * 3 + 1] * W3[j + 1] + W1[(k0 + 1) * 3 + 2] * W3[65 + j + 1];
      v0 = p0 * W2[j * 65 + k0 + 1];
      v1 = p1 * W2[j * 65 + k0 + 2];
    }
    unsigned short h0 = rne_bf16u(v0), h1 = rne_bf16u(v1);
    if (mat & 1) {  // lo plane = bf16 of residual
      h0 = rne_bf16u(v0 - bf16f(rne_bf16u(v0)));
      h1 = rne_bf16u(v1 - bf16f(rne_bf16u(v1)));
    }
    wsu[e2] = (uint)h0 | ((uint)h1 << 16);
  }
  if (tid < HDIM) {
    ws[8192 + tid * 4 + 0] = W1[tid * 3 + 0];
    ws[8192 + tid * 4 + 1] = W1[tid * 3 + 1];
    ws[8192 + tid * 4 + 2] = W1[tid * 3 + 2];
    ws[8192 + tid * 4 + 3] = b1[tid];
    ws[8448 + tid * 2 + 0] = W2[tid * 65 + 0];
    ws[8448 + tid * 2 + 1] = b2[tid];
    ws[8576 + tid * 2 + 0] = W3[tid + 1];
    ws[8576 + tid * 2 + 1] = W3[65 + tid + 1];
  }
  if (tid == 0) {
    ws[8704] = W3[0];
    ws[8705] = W3[65];
    ws[8706] = b3[0];
    ws[8707] = b3[1];
  }
}

// r10 pairing structure minus the spill: (1) stateLds removed — zt gathered by
// __shfl (wave-local, equivalent), LDS drops to 37888 B so 4 blocks/CU fit
// with margin; (2) A-frags packed INCREMENTALLY (d-pair at a time) so the
// sp[8]/sg[8] staging arrays never exist — cuts the transient peak that pushed
// r10 to 128+scratch. Numerics identical: 3-term bf16 hi/lo split both GEMMs,
// g kept f32. Checkpoint: WRITE_SIZE must return to ~3 MB (r10: 10.7 MB).
__global__ __launch_bounds__(256, 2) void ffjord_main(
    const float* __restrict__ z_in, const float* __restrict__ dlp_in,
    const float* __restrict__ ws, float* __restrict__ out, int B) {
  __shared__ uint4 fragLds[2048];        // 32 KB
  __shared__ float4 l1Lds[64];           // 1 KB
  __shared__ float2 c2Lds[64];           // 512 B
  __shared__ float2 l3Lds[64];           // 512 B
  __shared__ float  redLds[4][3][64];    // 3 KB   -> total 37888 B

  int tid = threadIdx.x;
  const uint4* wsu4 = (const uint4*)ws;
  #pragma unroll
  for (int j = 0; j < 8; ++j) fragLds[tid + 256 * j] = wsu4[tid + 256 * j];
  if (tid < 64) {
    l1Lds[tid] = ((const float4*)(ws + 8192))[tid];
    c2Lds[tid] = ((const float2*)(ws + 8448))[tid];
    l3Lds[tid] = ((const float2*)(ws + 8576))[tid];
  }
  __syncthreads();

  const float c30 = ws[8704], c31 = ws[8705], cb0 = ws[8706], cb1 = ws[8707];

  int wid = tid >> 6, l = tid & 63;
  int g = l >> 4, c = l & 15;
  int pt = blockIdx.x * 256 + wid * 64 + l;
  int ptc = pt < B ? pt : (B - 1);

  float z0 = z_in[2 * ptc], z1 = z_in[2 * ptc + 1];
  float lp = dlp_in[ptc];
  const float dt = 1.0f / NSTEPS;

  #pragma unroll 1
  for (int step = 0; step < NSTEPS; ++step) {
    float t0 = step * dt;
    float az0 = 0.f, az1 = 0.f, al = 0.f;
    float zt0 = z0, zt1 = z1, ts = t0;

    #pragma unroll 1
    for (int s = 0; s < 4; ++s) {
      float c2n[4];
      #pragma unroll
      for (int nt = 0; nt < 4; ++nt) {
        float2 cc = c2Lds[nt * 16 + c];
        c2n[nt] = fmaf(cc.x, ts, cc.y);
      }

      #pragma unroll 1
      for (int p = 0; p < 2; ++p) {
        asm volatile("" ::: "memory");  // pin pair-invariant LDS loads per pair
        int mtA = 2 * p, mtB = 2 * p + 1;
        // zt for this lane's A-rows, via wave-local shuffle (point = mt*16+c)
        float sA0 = __shfl(zt0, mtA * 16 + c);
        float sA1 = __shfl(zt1, mtA * 16 + c);
        float sB0 = __shfl(zt0, mtB * 16 + c);
        float sB1 = __shfl(zt1, mtB * 16 + c);

        // ---- A-frags for both row-tiles, packed incrementally ----
        FragU SPhA[2], SPlA[2], SGhA[2], SGlA[2];
        FragU SPhB[2], SPlB[2], SGhB[2], SGlB[2];
        #pragma unroll
        for (int kt = 0; kt < 2; ++kt) {
          #pragma unroll
          for (int d = 0; d < 4; ++d) {
            float4 p0 = l1Lds[kt * 32 + g * 8 + 2 * d];
            float4 p1 = l1Lds[kt * 32 + g * 8 + 2 * d + 1];
            float b0 = fmaf(p0.x, ts, p0.w);
            float b1 = fmaf(p1.x, ts, p1.w);
            float spA0, sgA0, spA1, sgA1, spB0, sgB0, spB1, sgB1;
            l1chain(p0, b0, sA0, sA1, spA0, sgA0);
            l1chain(p1, b1, sA0, sA1, spA1, sgA1);
            l1chain(p0, b0, sB0, sB1, spB0, sgB0);
            l1chain(p1, b1, sB0, sB1, spB1, sgB1);
            pack2(spA0, spA1, SPhA[kt].u[d], SPlA[kt].u[d]);
            pack2(sgA0, sgA1, SGhA[kt].u[d], SGlA[kt].u[d]);
            pack2(spB0, spB1, SPhB[kt].u[d], SPlB[kt].u[d]);
            pack2(sgB0, sgB1, SGhB[kt].u[d], SGlB[kt].u[d]);
          }
        }

        // ---- GEMM1 both rows, shared B reads ----
        f32x4 C1A[4], C1B[4];
        #pragma unroll
        for (int nt = 0; nt < 4; ++nt) {
          C1A[nt] = (f32x4){0.f, 0.f, 0.f, 0.f};
          C1B[nt] = (f32x4){0.f, 0.f, 0.f, 0.f};
        }
        #pragma unroll
        for (int kt = 0; kt < 2; ++kt) {
          #pragma unroll
          for (int nt = 0; nt < 4; ++nt) {
            FragU Bh, Bl;
            Bh.u4 = fragLds[(kt * 4 + nt) * 64 + l];
            Bl.u4 = fragLds[512 + (kt * 4 + nt) * 64 + l];
            C1A[nt] = __builtin_amdgcn_mfma_f32_16x16x32_bf16(SPhA[kt].v, Bh.v, C1A[nt], 0, 0, 0);
            C1B[nt] = __builtin_amdgcn_mfma_f32_16x16x32_bf16(SPhB[kt].v, Bh.v, C1B[nt], 0, 0, 0);
            C1A[nt] = __builtin_amdgcn_mfma_f32_16x16x32_bf16(SPhA[kt].v, Bl.v, C1A[nt], 0, 0, 0);
            C1B[nt] = __builtin_amdgcn_mfma_f32_16x16x32_bf16(SPhB[kt].v, Bl.v, C1B[nt], 0, 0, 0);
            C1A[nt] = __builtin_amdgcn_mfma_f32_16x16x32_bf16(SPlA[kt].v, Bh.v, C1A[nt], 0, 0, 0);
            C1B[nt] = __builtin_amdgcn_mfma_f32_16x16x32_bf16(SPlB[kt].v, Bh.v, C1B[nt], 0, 0, 0);
          }
        }

        // ---- mid both: zd partials, g = sigmoid(h2) f32 ----
        float zp0A[4] = {0.f, 0.f, 0.f, 0.f}, zp1A[4] = {0.f, 0.f, 0.f, 0.f};
        float zp0B[4] = {0.f, 0.f, 0.f, 0.f}, zp1B[4] = {0.f, 0.f, 0.f, 0.f};
        float gA[4][4], gB[4][4];
        #pragma unroll
        for (int nt = 0; nt < 4; ++nt) {
          float2 l3 = l3Lds[nt * 16 + c];
          #pragma unroll
          for (int r = 0; r < 4; ++r) {
            {
              float h2 = C1A[nt][r] + c2n[nt];
              float ex = __expf(-fabsf(h2));
              float rc = __builtin_amdgcn_rcpf(1.0f + ex);
              gA[nt][r] = (h2 >= 0.f ? 1.0f : ex) * rc;
              float sq = fmaxf(h2, 0.f) + __logf(1.0f + ex);
              zp0A[r] = fmaf(l3.x, sq, zp0A[r]);
              zp1A[r] = fmaf(l3.y, sq, zp1A[r]);
            }
            {
              float h2 = C1B[nt][r] + c2n[nt];
              float ex = __expf(-fabsf(h2));
              float rc = __builtin_amdgcn_rcpf(1.0f + ex);
              gB[nt][r] = (h2 >= 0.f ? 1.0f : ex) * rc;
              float sq = fmaxf(h2, 0.f) + __logf(1.0f + ex);
              zp0B[r] = fmaf(l3.x, sq, zp0B[r]);
              zp1B[r] = fmaf(l3.y, sq, zp1B[r]);
            }
          }
        }
        #pragma unroll
        for (int r = 0; r < 4; ++r) {
          zp0A[r] = row_sum16(zp0A[r]); zp1A[r] = row_sum16(zp1A[r]);
          zp0B[r] = row_sum16(zp0B[r]); zp1B[r] = row_sum16(zp1B[r]);
        }
        if (c == 0) {
          #pragma unroll
          for (int r = 0; r < 4; ++r) {
            redLds[wid][0][mtA * 16 + g * 4 + r] = zp0A[r];
            redLds[wid][1][mtA * 16 + g * 4 + r] = zp1A[r];
            redLds[wid][0][mtB * 16 + g * 4 + r] = zp0B[r];
            redLds[wid][1][mtB * 16 + g * 4 + r] = zp1B[r];
          }
        }

        // ---- GEMM2 both rows, shared B reads; dv += R .* g ----
        float dvA[4] = {0.f, 0.f, 0.f, 0.f}, dvB[4] = {0.f, 0.f, 0.f, 0.f};
        #pragma unroll
        for (int nt = 0; nt < 4; ++nt) {
          f32x4 C2A = (f32x4){0.f, 0.f, 0.f, 0.f};
          f32x4 C2B = (f32x4){0.f, 0.f, 0.f, 0.f};
          #pragma unroll
          for (int kt = 0; kt < 2; ++kt) {
            FragU Bh, Bl;
            Bh.u4 = fragLds[1024 + (kt * 4 + nt) * 64 + l];
            Bl.u4 = fragLds[1536 + (kt * 4 + nt) * 64 + l];
            C2A = __builtin_amdgcn_mfma_f32_16x16x32_bf16(SGhA[kt].v, Bh.v, C2A, 0, 0, 0);
            C2B = __builtin_amdgcn_mfma_f32_16x16x32_bf16(SGhB[kt].v, Bh.v, C2B, 0, 0, 0);
            C2A = __builtin_amdgcn_mfma_f32_16x16x32_bf16(SGhA[kt].v, Bl.v, C2A, 0, 0, 0);
            C2B = __builtin_amdgcn_mfma_f32_16x16x32_bf16(SGhB[kt].v, Bl.v, C2B, 0, 0, 0);
            C2A = __builtin_amdgcn_mfma_f32_16x16x32_bf16(SGlA[kt].v, Bh.v, C2A, 0, 0, 0);
            C2B = __builtin_amdgcn_mfma_f32_16x16x32_bf16(SGlB[kt].v, Bh.v, C2B, 0, 0, 0);
          }
          #pragma unroll
          for (int r = 0; r < 4; ++r) {
            dvA[r] = fmaf(C2A[r], gA[nt][r], dvA[r]);
            dvB[r] = fmaf(C2B[r], gB[nt][r], dvB[r]);
          }
        }
        #pragma unroll
        for (int r = 0; r < 4; ++r) {
          dvA[r] = row_sum16(dvA[r]);
          dvB[r] = row_sum16(dvB[r]);
        }
        if (c == 0) {
          #pragma unroll
          for (int r = 0; r < 4; ++r) {
            redLds[wid][2][mtA * 16 + g * 4 + r] = dvA[r];
            redLds[wid][2][mtB * 16 + g * 4 + r] = dvB[r];
          }
        }
      }

      // ---- owner: collect zd/dv, RK4 ----
      float zd0 = redLds[wid][0][l] + fmaf(c30, ts, cb0);
      float zd1 = redLds[wid][1][l] + fmaf(c31, ts, cb1);
      float dv  = redLds[wid][2][l];

      float w = (s == 1 || s == 2) ? 2.0f : 1.0f;
      az0 = fmaf(w, zd0, az0);
      az1 = fmaf(w, zd1, az1);
      al  = fmaf(w, dv, al);
      if (s < 3) {
        float cc2 = (s == 2) ? dt : 0.5f * dt;
        zt0 = fmaf(cc2, zd0, z0);
        zt1 = fmaf(cc2, zd1, z1);
        ts = t0 + cc2;
      }
    }
    z0 = fmaf(dt / 6.0f, az0, z0);
    z1 = fmaf(dt / 6.0f, az1, z1);
    lp = fmaf(-dt / 6.0f, al, lp);  // k_l = -div
  }

  if (pt < B) {
    out[2 * pt] = z0;
    out[2 * pt + 1] = z1;
    out[2 * B + pt] = lp;
  }
}

extern "C" void kernel_launch(void* const* d_in, const int* in_sizes, int n_in,
                              void* d_out, int out_size, void* d_ws, size_t ws_size,
                              hipStream_t stream) {
  const float* z   = (const float*)d_in[0];
  const float* dlp = (const float*)d_in[1];
  const float* W1  = (const float*)d_in[2];
  const float* b1  = (const float*)d_in[3];
  const float* W2  = (const float*)d_in[4];
  const float* b2  = (const float*)d_in[5];
  const float* W3  = (const float*)d_in[6];
  const float* b3  = (const float*)d_in[7];
  float* out = (float*)d_out;
  float* ws = (float*)d_ws;

  int B = in_sizes[0] / 2;

  ffjord_prep<<<1, 256, 0, stream>>>(W1, b1, W2, b2, W3, b3, ws);
  int blocks = (B + 255) / 256;  // 256 points per block, 64 per wave
  ffjord_main<<<blocks, 256, 0, stream>>>(z, dlp, ws, out, B);
}